// Round 14
// baseline (479.719 us; speedup 1.0000x reference)
//
#include <hip/hip_runtime.h>

// ---------------------------------------------------------------------------
// Fused per-sample attention-critic network, MI355X (gfx950).
// r13 base (457us best) + two instruction/spill-removing changes:
// (1) PV runs samples sequentially (lambda x2) -> peak reg pressure down,
//     kills the 12MB scratch spill r13 introduced;
// (2) LN normalize on the trivial-affine fast path uses packed f16 FMA
//     (v_pk_fma_f16): 1 instr per pair vs 5 (cvt/fma/pack) — ~290 fewer
//     instructions per pair. Exact f32 path kept for non-trivial gains.
// ---------------------------------------------------------------------------

typedef __fp16 h2 __attribute__((ext_vector_type(2)));
typedef h2     h2a  __attribute__((may_alias));
typedef float4 f4a  __attribute__((may_alias));
typedef float2 f2a  __attribute__((may_alias));
typedef __fp16 f16a __attribute__((may_alias));

__device__ __forceinline__ h2 pkh2(float a, float b) {
#if __has_builtin(__builtin_amdgcn_cvt_pkrtz)
  return __builtin_amdgcn_cvt_pkrtz(a, b);
#else
  h2 r; r.x = (__fp16)a; r.y = (__fp16)b; return r;
#endif
}
__device__ __forceinline__ h2    f_h2(float f) { return __builtin_bit_cast(h2, f); }
__device__ __forceinline__ float h2_f(h2 v)    { return __builtin_bit_cast(float, v); }

__device__ __forceinline__ float fdot2(h2 a, h2 b, float c) {
#if __has_builtin(__builtin_amdgcn_fdot2)
  return __builtin_amdgcn_fdot2(a, b, c, false);
#else
  return c + (float)a.x * (float)b.x + (float)a.y * (float)b.y;
#endif
}
__device__ __forceinline__ float rcpf(float x) {
#if __has_builtin(__builtin_amdgcn_rcpf)
  return __builtin_amdgcn_rcpf(x);
#else
  return 1.f / x;
#endif
}
__device__ __forceinline__ float tanhf_fast(float x) {
  float e = __expf(2.f * x);                 // inf-safe
  return 1.f - 2.f * rcpf(e + 1.f);
}
__device__ __forceinline__ float eluf(float x) {
  return x > 0.f ? x : __expf(x) - 1.f;
}

#if __has_builtin(__builtin_amdgcn_update_dpp)
#define HAVE_DPP 1
#else
#define HAVE_DPP 0
#endif

// Full-wave (64-lane) f32 sum via DPP; result broadcast to all lanes.
__device__ __forceinline__ float wred_add(float x) {
#if HAVE_DPP
  float v = x;
  { int t = __builtin_amdgcn_update_dpp(0, __builtin_bit_cast(int, v), 0x111, 0xf, 0xf, true);
    v = v + __builtin_bit_cast(float, t); }   // row_shr:1
  { int t = __builtin_amdgcn_update_dpp(0, __builtin_bit_cast(int, v), 0x112, 0xf, 0xf, true);
    v = v + __builtin_bit_cast(float, t); }   // row_shr:2
  { int t = __builtin_amdgcn_update_dpp(0, __builtin_bit_cast(int, v), 0x114, 0xf, 0xf, true);
    v = v + __builtin_bit_cast(float, t); }   // row_shr:4
  { int t = __builtin_amdgcn_update_dpp(0, __builtin_bit_cast(int, v), 0x118, 0xf, 0xf, true);
    v = v + __builtin_bit_cast(float, t); }   // row_shr:8
  { int t = __builtin_amdgcn_update_dpp(0, __builtin_bit_cast(int, v), 0x142, 0xa, 0xf, true);
    v = v + __builtin_bit_cast(float, t); }   // row_bcast:15 -> rows 1,3
  { int t = __builtin_amdgcn_update_dpp(0, __builtin_bit_cast(int, v), 0x143, 0xc, 0xf, true);
    v = v + __builtin_bit_cast(float, t); }   // row_bcast:31 -> rows 2,3
  return __builtin_bit_cast(float, __builtin_amdgcn_readlane(__builtin_bit_cast(int, v), 63));
#else
  #pragma unroll
  for (int m2 = 1; m2 < 64; m2 <<= 1) x += __shfl_xor(x, m2, 64);
  return x;
#endif
}

// 16-lane (DPP-row) all-lane sum via rotate-accumulate.
__device__ __forceinline__ float dpp_add16(float x) {
#if HAVE_DPP
  float v = x;
  { int t = __builtin_amdgcn_update_dpp(0, __builtin_bit_cast(int, v), 0x121, 0xf, 0xf, true);
    v = v + __builtin_bit_cast(float, t); }   // row_ror:1
  { int t = __builtin_amdgcn_update_dpp(0, __builtin_bit_cast(int, v), 0x122, 0xf, 0xf, true);
    v = v + __builtin_bit_cast(float, t); }   // row_ror:2
  { int t = __builtin_amdgcn_update_dpp(0, __builtin_bit_cast(int, v), 0x124, 0xf, 0xf, true);
    v = v + __builtin_bit_cast(float, t); }   // row_ror:4
  { int t = __builtin_amdgcn_update_dpp(0, __builtin_bit_cast(int, v), 0x128, 0xf, 0xf, true);
    v = v + __builtin_bit_cast(float, t); }   // row_ror:8
  return v;
#else
  #pragma unroll
  for (int m2 = 1; m2 < 16; m2 <<= 1) x += __shfl_xor(x, m2, 64);
  return x;
#endif
}

// 16-lane (DPP-row) all-lane max via rotate-accumulate.
__device__ __forceinline__ float dpp_max16(float x) {
#if HAVE_DPP
  float v = x;
  { int t = __builtin_amdgcn_update_dpp(0, __builtin_bit_cast(int, v), 0x121, 0xf, 0xf, true);
    v = fmaxf(v, __builtin_bit_cast(float, t)); }
  { int t = __builtin_amdgcn_update_dpp(0, __builtin_bit_cast(int, v), 0x122, 0xf, 0xf, true);
    v = fmaxf(v, __builtin_bit_cast(float, t)); }
  { int t = __builtin_amdgcn_update_dpp(0, __builtin_bit_cast(int, v), 0x124, 0xf, 0xf, true);
    v = fmaxf(v, __builtin_bit_cast(float, t)); }
  { int t = __builtin_amdgcn_update_dpp(0, __builtin_bit_cast(int, v), 0x128, 0xf, 0xf, true);
    v = fmaxf(v, __builtin_bit_cast(float, t)); }
  return v;
#else
  #pragma unroll
  for (int m2 = 1; m2 < 16; m2 <<= 1) x = fmaxf(x, __shfl_xor(x, m2, 64));
  return x;
#endif
}

// ---------------------------------------------------------------------------
// s_mem (BYTES): staging [0,9728) dead after pre-loop reg loads (barrier),
// then 8 per-(wave,sample) arenas of 8352 B: wave wv owns
//   arenaA = s_mem + wv*16704, arenaB = arenaA + 8352.
// Arena: xs [0,288) 72 h2 | kqv [288,5664) 1344 h2 | Ab [5664,8352) 672 f32.
// (288+5376+2688 = 8352 exactly; identical to r8..r13 verified layout.)
// ---------------------------------------------------------------------------
__global__ __launch_bounds__(256, 2) void fused_main(
    const float* __restrict__ x,
    const float* __restrict__ kw,   const float* __restrict__ kb,
    const float* __restrict__ qw,   const float* __restrict__ qb,
    const float* __restrict__ vw,   const float* __restrict__ vb,
    const float* __restrict__ kng,  const float* __restrict__ knb,
    const float* __restrict__ qng,  const float* __restrict__ qnb,
    const float* __restrict__ vng,  const float* __restrict__ vnb,
    const float* __restrict__ klinw, const float* __restrict__ klinb,
    const float* __restrict__ qlinw, const float* __restrict__ qlinb,
    const float* __restrict__ alinw, const float* __restrict__ alinb,
    const float* __restrict__ l1w,  const float* __restrict__ l1b,
    const float* __restrict__ l2w,  const float* __restrict__ l2b,
    float* __restrict__ out, int B)
{
  __shared__ __align__(16) unsigned char s_mem[8 * 8352];  // 66816 B
  __shared__ __align__(16) h2 s_l1w[32 * 50];   // stride 100B, conflict-free
  __shared__ float s_l1b[32];
  __shared__ float s_l2w[32];
  __shared__ float s_l2b[1];
  __shared__ unsigned s_gflags;

  const int tid = threadIdx.x;

  // ---- staging views (valid only until the post-reg-load barrier) ----
  h2*    st_pw  = (h2*)(s_mem);
  float* st_pb  = (float*)(s_mem + 5760);
  h2*    st_qlw = (h2*)(s_mem + 6912);
  h2*    st_klw = (h2*)(s_mem + 7808);
  float* st_alw = (float*)(s_mem + 8704);
  float* st_bqk = (float*)(s_mem + 9600);
  float* st_ab  = (float*)(s_mem + 9664);

  for (int i = tid; i < 1440; i += 256) {
    int C = i / 5, f2 = i - 5 * C;
    int t = C / 96, c = C - 96 * t;
    const float* w = (t == 0) ? kw : (t == 1) ? qw : vw;
    st_pw[i] = pkh2(w[c * 10 + 2 * f2], w[c * 10 + 2 * f2 + 1]);
  }
  for (int i = tid; i < 288; i += 256) {
    int t = i / 96, c = i - 96 * t;
    st_pb[i] = ((t == 0) ? kb : (t == 1) ? qb : vb)[c];
  }
  for (int i = tid; i < 224; i += 256) {
    int n = i >> 4, d2 = i & 15;
    st_qlw[i] = pkh2(qlinw[n * 32 + 2 * d2], qlinw[n * 32 + 2 * d2 + 1]);
    st_klw[i] = pkh2(klinw[n * 32 + 2 * d2], klinw[n * 32 + 2 * d2 + 1]);
    st_alw[i] = (d2 < 14) ? alinw[n * 14 + d2] : 0.f;
  }
  if (tid < 14)             { st_bqk[tid] = qlinb[tid] + klinb[tid]; st_ab[tid] = alinb[tid]; }
  if (tid >= 14 && tid < 16){ st_bqk[tid] = 0.f; st_ab[tid] = 0.f; }
  for (int i = tid; i < 1600; i += 256) {
    int j = i / 50, c2 = i - 50 * j;
    s_l1w[i] = (c2 < 48) ? pkh2(l1w[j * 96 + 2 * c2], l1w[j * 96 + 2 * c2 + 1])
                         : pkh2(0.f, 0.f);
  }
  if (tid < 32) { s_l1b[tid] = l1b[tid]; s_l2w[tid] = l2w[tid]; }
  if (tid == 0) { s_l2b[0] = l2b[0]; s_gflags = 7u; }
  __syncthreads();
  for (int i = tid; i < 1344; i += 256) {
    if (kng[i] != 1.f || knb[i] != 0.f) atomicAnd(&s_gflags, ~1u);
    if (qng[i] != 1.f || qnb[i] != 0.f) atomicAnd(&s_gflags, ~2u);
    if (vng[i] != 1.f || vnb[i] != 0.f) atomicAnd(&s_gflags, ~4u);
  }
  __syncthreads();

  const int lane = tid & 63;
  const int wv   = tid >> 6;
  h2*    arenaA = (h2*)(s_mem + wv * 16704);
  h2*    arenaB = (h2*)(s_mem + wv * 16704 + 8352);
  h2     *xsA = arenaA, *xsB = arenaB;
  h2     *kqvA = arenaA + 72, *kqvB = arenaB + 72;        // h2 off 72 = byte 288
  f16a   *kqvhA = (f16a*)kqvA, *kqvhB = (f16a*)kqvB;
  float  *AbA = (float*)((unsigned char*)arenaA + 5664);
  float  *AbB = (float*)((unsigned char*)arenaB + 5664);
  const unsigned gf = s_gflags;

  // ---- persistent per-lane weight registers (from staging LDS, once) ----
  h2 pwA[3][5]; float pbA[3]; int cbA[3];
  #pragma unroll
  for (int k = 0; k < 3; ++k) {
    int C = lane + 64 * k;
    #pragma unroll
    for (int f2 = 0; f2 < 5; ++f2) pwA[k][f2] = st_pw[C * 5 + f2];
    pbA[k] = st_pb[C];
    int t = (C >= 96) ? 1 : 0, c = C - 96 * t;
    cbA[k] = t * 1344 + (c >> 5) * 448 + (c & 31);   // f16 idx (kqvh-relative)
  }
  h2 pwB[2][5]; float pbB[2]; int cbB[2]; bool actB[2];
  #pragma unroll
  for (int k = 0; k < 2; ++k) {
    int c = lane + 64 * k;
    actB[k] = (c < 96);
    int cc = actB[k] ? c : 0;
    #pragma unroll
    for (int f2 = 0; f2 < 5; ++f2) pwB[k][f2] = st_pw[(192 + cc) * 5 + f2];
    pbB[k] = st_pb[192 + cc];
    cbB[k] = (cc >> 5) * 448 + (cc & 31);
  }
  const int np  = lane & 15, grp = lane >> 4;
  const int npc = (np < 14) ? np : 0;
  h2 qwr[16], kwr[16];
  #pragma unroll
  for (int i = 0; i < 16; ++i) { qwr[i] = st_qlw[npc * 16 + i]; kwr[i] = st_klw[npc * 16 + i]; }
  const float bqkr = st_bqk[npc];
  float awr[14];
  #pragma unroll
  for (int i = 0; i < 14; ++i) awr[i] = st_alw[npc * 16 + i];
  const float abr  = st_ab[npc];
  const int j32 = lane & 31, g2 = lane >> 5;
  const float l1br = s_l1b[j32];
  const float l2r  = s_l2w[j32];
  const float l2bb = s_l2b[0];

  // staging is DEAD after this barrier; arenas become live
  __syncthreads();

  // l1 weights: loop-invariant -> hoist out of the pair loop
  h2 lwr[48];
  #pragma unroll
  for (int i = 0; i < 48; ++i) lwr[i] = s_l1w[j32 * 50 + i];

  h2 one2; one2.x = (__fp16)1.f; one2.y = (__fp16)1.f;
  const bool has3 = (lane < 40);               // 168 f4 chunks = 64+64+40

  // Paired LayerNorm over two 1344-f16 tensors (independent chains interleave)
  auto doLN2 = [&](h2* regA, h2* regB, const float* gp, const float* bp, bool triv) {
    const f4a* tA = (const f4a*)regA;
    const f4a* tB = (const f4a*)regB;
    float4 a0 = tA[lane],  a1 = tA[lane + 64], a2 = tA[has3 ? (lane + 128) : 0];
    float4 b0 = tB[lane],  b1 = tB[lane + 64], b2 = tB[has3 ? (lane + 128) : 0];
    if (!has3) { a2.x=a2.y=a2.z=a2.w=0.f; b2.x=b2.y=b2.z=b2.w=0.f; }
    float sA = 0.f, qA = 0.f, sB = 0.f, qB = 0.f;
    {
      float fa[12] = {a0.x,a0.y,a0.z,a0.w, a1.x,a1.y,a1.z,a1.w, a2.x,a2.y,a2.z,a2.w};
      float fb[12] = {b0.x,b0.y,b0.z,b0.w, b1.x,b1.y,b1.z,b1.w, b2.x,b2.y,b2.z,b2.w};
      #pragma unroll
      for (int i = 0; i < 12; ++i) {
        h2 ha = f_h2(fa[i]); sA = fdot2(ha, one2, sA); qA = fdot2(ha, ha, qA);
        h2 hb = f_h2(fb[i]); sB = fdot2(hb, one2, sB); qB = fdot2(hb, hb, qB);
      }
    }
    sA = wred_add(sA); qA = wred_add(qA);
    sB = wred_add(sB); qB = wred_add(qB);
    const float mA = sA * (1.f / 1344.f), mB = sB * (1.f / 1344.f);
    const float vA = qA * (1.f / 1344.f) - mA * mA;
    const float vB = qB * (1.f / 1344.f) - mB * mB;
    const float cA = rsqrtf(vA + 1e-5f),  cB = rsqrtf(vB + 1e-5f);
    const float dA = -mA * cA,            dB = -mB * cB;
    f4a* wA = (f4a*)regA;
    f4a* wB = (f4a*)regB;
    if (triv) {
      // packed f16 normalize: 1 v_pk_fma_f16 per h2 pair
      h2 scA2 = pkh2(cA, cA), msA2 = pkh2(dA, dA);
      h2 scB2 = pkh2(cB, cB), msB2 = pkh2(dB, dB);
      auto nst = [&](float4 rv, int o, bool en, h2 s2, h2 m2, f4a* dst) {
        if (!en) return;
        float4 o4;
        o4.x = h2_f(f_h2(rv.x) * s2 + m2);
        o4.y = h2_f(f_h2(rv.y) * s2 + m2);
        o4.z = h2_f(f_h2(rv.z) * s2 + m2);
        o4.w = h2_f(f_h2(rv.w) * s2 + m2);
        dst[o] = o4;
      };
      nst(a0, lane,       true, scA2, msA2, wA); nst(b0, lane,       true, scB2, msB2, wB);
      nst(a1, lane + 64,  true, scA2, msA2, wA); nst(b1, lane + 64,  true, scB2, msB2, wB);
      nst(a2, lane + 128, has3, scA2, msA2, wA); nst(b2, lane + 128, has3, scB2, msB2, wB);
    } else {
      auto nstore = [&](float4 rv, int o, bool en, float sc, float msc, f4a* dst) {
        if (!en) return;
        h2 ha = f_h2(rv.x), hb = f_h2(rv.y), hc = f_h2(rv.z), hd = f_h2(rv.w);
        float f[8];
        f[0] = (float)ha.x * sc + msc; f[1] = (float)ha.y * sc + msc;
        f[2] = (float)hb.x * sc + msc; f[3] = (float)hb.y * sc + msc;
        f[4] = (float)hc.x * sc + msc; f[5] = (float)hc.y * sc + msc;
        f[6] = (float)hd.x * sc + msc; f[7] = (float)hd.y * sc + msc;
        #pragma unroll
        for (int i = 0; i < 8; ++i) { int e = 8 * o + i; f[i] = f[i] * gp[e] + bp[e]; }
        float4 o4;
        o4.x = h2_f(pkh2(f[0], f[1])); o4.y = h2_f(pkh2(f[2], f[3]));
        o4.z = h2_f(pkh2(f[4], f[5])); o4.w = h2_f(pkh2(f[6], f[7]));
        dst[o] = o4;
      };
      nstore(a0, lane,       true, cA, dA, wA); nstore(b0, lane,       true, cB, dB, wB);
      nstore(a1, lane + 64,  true, cA, dA, wA); nstore(b1, lane + 64,  true, cB, dB, wB);
      nstore(a2, lane + 128, has3, cA, dA, wA); nstore(b2, lane + 128, has3, cB, dB, wB);
    }
  };

  // PV for ONE sample (lower register pressure than paired; 8 acc chains)
  auto doPV = [&](h2* kqv, float* Ab) {
    #pragma unroll
    for (int h = 0; h < 3; ++h) {
      h2 vreg[14];
      {
        const h2a* V = (const h2a*)(kqv + h * 224 + np);
        #pragma unroll
        for (int m = 0; m < 14; ++m) vreg[m] = V[m * 16];
      }
      // rows of head h congruent to grp (mod 4): delta = (grp + 2*(h&1)) & 3
      const int base = h * 14 + ((grp + 2 * (h & 1)) & 3);
      #pragma unroll
      for (int i = 0; i < 4; ++i) {
        int rr = base + 4 * i;
        bool act = (rr < h * 14 + 14);
        int rrc = act ? rr : h * 14;
        int n = rrc - 14 * h;
        const f4a* P4 = (const f4a*)(Ab + rrc * 16);
        float4 P0 = P4[0], P1 = P4[1], P2 = P4[2], P3 = P4[3];
        float pr[14] = {P0.x,P0.y,P0.z,P0.w, P1.x,P1.y,P1.z,P1.w,
                        P2.x,P2.y,P2.z,P2.w, P3.x,P3.y};
        float ax = 0.f, ay = 0.f;
        #pragma unroll
        for (int m = 0; m < 14; ++m) {
          ax += pr[m] * (float)vreg[m].x;
          ay += pr[m] * (float)vreg[m].y;
        }
        if (act) kqv[672 + n * 48 + h * 16 + np] = pkh2(ax, ay);
      }
    }
  };

  const int pid = blockIdx.x * 4 + wv;      // pair index
  const int pstr = gridDim.x * 4;

  for (int s0 = pid * 2; s0 < B; s0 += pstr * 2) {
    const int s1 = s0 + 1;
    const bool has1 = (s1 < B);
    const int s1c = has1 ? s1 : s0;

    // ---------------- stage x (2 samples) ----------------
    const f2a* xpA = (const f2a*)(x + (size_t)s0  * 140);
    const f2a* xpB = (const f2a*)(x + (size_t)s1c * 140);
    { f2a vA = xpA[lane], vB = xpB[lane];
      xsA[lane] = pkh2(vA.x, vA.y); xsB[lane] = pkh2(vB.x, vB.y); }
    if (lane < 6) {
      f2a vA = xpA[64 + lane], vB = xpB[64 + lane];
      xsA[64 + lane] = pkh2(vA.x, vA.y); xsB[64 + lane] = pkh2(vB.x, vB.y);
    }

    // ============ PHASE A: K,Q projections (paired) ============
    for (int n = 0; n < 14; ++n) {
      h2 a0=xsA[n*5+0],a1=xsA[n*5+1],a2=xsA[n*5+2],a3=xsA[n*5+3],a4=xsA[n*5+4];
      h2 c0=xsB[n*5+0],c1=xsB[n*5+1],c2=xsB[n*5+2],c3=xsB[n*5+3],c4=xsB[n*5+4];
      #pragma unroll
      for (int k = 0; k < 3; ++k) {
        float uA = pbA[k], uB = pbA[k];
        uA = fdot2(a0, pwA[k][0], uA); uB = fdot2(c0, pwA[k][0], uB);
        uA = fdot2(a1, pwA[k][1], uA); uB = fdot2(c1, pwA[k][1], uB);
        uA = fdot2(a2, pwA[k][2], uA); uB = fdot2(c2, pwA[k][2], uB);
        uA = fdot2(a3, pwA[k][3], uA); uB = fdot2(c3, pwA[k][3], uB);
        uA = fdot2(a4, pwA[k][4], uA); uB = fdot2(c4, pwA[k][4], uB);
        kqvhA[cbA[k] + n * 32] = (__fp16)uA;
        kqvhB[cbA[k] + n * 32] = (__fp16)uB;
      }
    }
    doLN2(kqvA,       kqvB,       kng, knb, (gf >> 0) & 1u);   // K pair
    doLN2(kqvA + 672, kqvB + 672, qng, qnb, (gf >> 1) & 1u);   // Q pair

    // ------- scores (paired): elu(Q·qlw + K·klw + b) -------
    for (int k = 0; k <= 10; ++k) {
      int r = grp + 4 * k;
      bool act = (np < 14) && (r < 42);
      int rr = (r < 42) ? r : 0;
      const f4a* KrA = (const f4a*)(kqvA + rr * 16);
      const f4a* QrA = (const f4a*)(kqvA + 672 + rr * 16);
      const f4a* KrB = (const f4a*)(kqvB + rr * 16);
      const f4a* QrB = (const f4a*)(kqvB + 672 + rr * 16);
      float aqA = bqkr, akA = 0.f, aqB = bqkr, akB = 0.f;
      #pragma unroll
      for (int q = 0; q < 4; ++q) {
        float4 qvA = QrA[q], kvA = KrA[q], qvB = QrB[q], kvB = KrB[q];
        aqA = fdot2(f_h2(qvA.x), qwr[4*q+0], aqA); aqB = fdot2(f_h2(qvB.x), qwr[4*q+0], aqB);
        aqA = fdot2(f_h2(qvA.y), qwr[4*q+1], aqA); aqB = fdot2(f_h2(qvB.y), qwr[4*q+1], aqB);
        aqA = fdot2(f_h2(qvA.z), qwr[4*q+2], aqA); aqB = fdot2(f_h2(qvB.z), qwr[4*q+2], aqB);
        aqA = fdot2(f_h2(qvA.w), qwr[4*q+3], aqA); aqB = fdot2(f_h2(qvB.w), qwr[4*q+3], aqB);
        akA = fdot2(f_h2(kvA.x), kwr[4*q+0], akA); akB = fdot2(f_h2(kvB.x), kwr[4*q+0], akB);
        akA = fdot2(f_h2(kvA.y), kwr[4*q+1], akA); akB = fdot2(f_h2(kvB.y), kwr[4*q+1], akB);
        akA = fdot2(f_h2(kvA.z), kwr[4*q+2], akA); akB = fdot2(f_h2(kvB.z), kwr[4*q+2], akB);
        akA = fdot2(f_h2(kvA.w), kwr[4*q+3], akA); akB = fdot2(f_h2(kvB.w), kwr[4*q+3], akB);
      }
      float aA = eluf(aqA + akA), aB = eluf(aqB + akB);
      if (act) { AbA[rr * 16 + np] = aA; AbB[rr * 16 + np] = aB; }
    }

    // ------- alin + softmax (paired; DPP row reductions) -------
    for (int k = 0; k <= 10; ++k) {
      int r = grp + 4 * k;
      bool act = (np < 14) && (r < 42);
      int rr = (r < 42) ? r : 0;
      const f4a* SA = (const f4a*)(AbA + rr * 16);
      const f4a* SB = (const f4a*)(AbB + rr * 16);
      float4 A0 = SA[0], A1 = SA[1], A2 = SA[2], A3 = SA[3];
      float4 B0 = SB[0], B1 = SB[1], B2 = SB[2], B3 = SB[3];
      float prA[14] = {A0.x,A0.y,A0.z,A0.w, A1.x,A1.y,A1.z,A1.w,
                       A2.x,A2.y,A2.z,A2.w, A3.x,A3.y};
      float prB[14] = {B0.x,B0.y,B0.z,B0.w, B1.x,B1.y,B1.z,B1.w,
                       B2.x,B2.y,B2.z,B2.w, B3.x,B3.y};
      float acA = abr, acB = abr;
      #pragma unroll
      for (int i = 0; i < 14; ++i) { acA += prA[i] * awr[i]; acB += prB[i] * awr[i]; }
      float vA = act ? acA : -__builtin_inff();
      float vB = act ? acB : -__builtin_inff();
      float mA = dpp_max16(vA);
      float mB = dpp_max16(vB);
      float eA = __expf(vA - mA), eB = __expf(vB - mB);   // inactive lanes -> 0
      float sA = dpp_add16(eA);
      float sB = dpp_add16(eB);
      float pA = eA * rcpf(sA), pB = eB * rcpf(sB);
      if (act) { AbA[rr * 16 + np] = pA; AbB[rr * 16 + np] = pB; }
    }

    // ============ PHASE B: V projection (paired, overlays K) ============
    for (int n = 0; n < 14; ++n) {
      h2 a0=xsA[n*5+0],a1=xsA[n*5+1],a2=xsA[n*5+2],a3=xsA[n*5+3],a4=xsA[n*5+4];
      h2 c0=xsB[n*5+0],c1=xsB[n*5+1],c2=xsB[n*5+2],c3=xsB[n*5+3],c4=xsB[n*5+4];
      #pragma unroll
      for (int k = 0; k < 2; ++k) {
        float uA = pbB[k], uB = pbB[k];
        uA = fdot2(a0, pwB[k][0], uA); uB = fdot2(c0, pwB[k][0], uB);
        uA = fdot2(a1, pwB[k][1], uA); uB = fdot2(c1, pwB[k][1], uB);
        uA = fdot2(a2, pwB[k][2], uA); uB = fdot2(c2, pwB[k][2], uB);
        uA = fdot2(a3, pwB[k][3], uA); uB = fdot2(c3, pwB[k][3], uB);
        uA = fdot2(a4, pwB[k][4], uA); uB = fdot2(c4, pwB[k][4], uB);
        if (actB[k]) {
          kqvhA[cbB[k] + n * 32] = (__fp16)uA;
          kqvhB[cbB[k] + n * 32] = (__fp16)uB;
        }
      }
    }
    doLN2(kqvA, kqvB, vng, vnb, (gf >> 2) & 1u);   // V pair (overlaid K region)

    // ------- E = A@V: per-sample (register pressure), V reg-cached per head --
    doPV(kqvA, AbA);
    doPV(kqvB, AbB);

    // ------- l1 (paired, hoisted lwr): E2 = relu(E·l1w + b) -------
    for (int k = 0; k < 7; ++k) {
      int n = g2 + 2 * k;
      const f4a* EA = (const f4a*)(kqvA + 672 + n * 48);
      const f4a* EB = (const f4a*)(kqvB + 672 + n * 48);
      float u0A = l1br, u1A = 0.f, u0B = l1br, u1B = 0.f;
      #pragma unroll
      for (int q = 0; q < 12; ++q) {
        float4 eA = EA[q], eB = EB[q];
        u0A = fdot2(f_h2(eA.x), lwr[4*q+0], u0A); u0B = fdot2(f_h2(eB.x), lwr[4*q+0], u0B);
        u1A = fdot2(f_h2(eA.y), lwr[4*q+1], u1A); u1B = fdot2(f_h2(eB.y), lwr[4*q+1], u1B);
        u0A = fdot2(f_h2(eA.z), lwr[4*q+2], u0A); u0B = fdot2(f_h2(eB.z), lwr[4*q+2], u0B);
        u1A = fdot2(f_h2(eA.w), lwr[4*q+3], u1A); u1B = fdot2(f_h2(eB.w), lwr[4*q+3], u1B);
      }
      AbA[n * 32 + j32] = fmaxf(u0A + u1A, 0.f);
      AbB[n * 32 + j32] = fmaxf(u0B + u1B, 0.f);
    }

    // ------- LN2 (paired, DPP) + max_n + l2 -> y -------
    {
      float vlA[7], vlB[7];
      #pragma unroll
      for (int m = 0; m < 7; ++m) { vlA[m] = AbA[lane + 64 * m]; vlB[m] = AbB[lane + 64 * m]; }
      float sA = 0.f, qA = 0.f, sB = 0.f, qB = 0.f;
      #pragma unroll
      for (int m = 0; m < 7; ++m) {
        sA += vlA[m]; qA += vlA[m] * vlA[m];
        sB += vlB[m]; qB += vlB[m] * vlB[m];
      }
      sA = wred_add(sA); qA = wred_add(qA);
      sB = wred_add(sB); qB = wred_add(qB);
      float mnA = sA * (1.f / 448.f), mnB = sB * (1.f / 448.f);
      float vrA = qA * (1.f / 448.f) - mnA * mnA;
      float vrB = qB * (1.f / 448.f) - mnB * mnB;
      float scA = rsqrtf(vrA + 1e-5f), scB = rsqrtf(vrB + 1e-5f);
      float mxA = -__builtin_inff(), mxB = -__builtin_inff();
      #pragma unroll
      for (int k = 0; k < 7; ++k) {
        mxA = fmaxf(mxA, AbA[(g2 + 2 * k) * 32 + j32]);
        mxB = fmaxf(mxB, AbB[(g2 + 2 * k) * 32 + j32]);
      }
      mxA = fmaxf(mxA, __shfl_xor(mxA, 32, 64));
      mxB = fmaxf(mxB, __shfl_xor(mxB, 32, 64));
      float MdA = (mxA - mnA) * scA;            // scale>0: max commutes with LN
      float MdB = (mxB - mnB) * scB;
      float vdA = wred_add((lane < 32) ? MdA * l2r : 0.f);
      float vdB = wred_add((lane < 32) ? MdB * l2r : 0.f);
      float yA = eluf(vdA + l2bb), yB = eluf(vdB + l2bb);
      if (lane == 0) { out[s0] = yA; if (has1) out[s1] = yB; }
    }
  }
}

// ---------------------------------------------------------------------------
// Kernel 2: out[s] = sigmoid(fc3 · tanh(fc2 · tanh(fc1*y + b1) + b2) + b3)
// Applied in place on d_out (kernel 1 left y there).
// ---------------------------------------------------------------------------
__global__ __launch_bounds__(256) void mlp_head(
    float* __restrict__ out,
    const float* __restrict__ fc1w, const float* __restrict__ fc1b,
    const float* __restrict__ fc2w, const float* __restrict__ fc2b,
    const float* __restrict__ fc3w, const float* __restrict__ fc3b, int B)
{
  __shared__ float s1w[100], s1b[100];
  __shared__ __align__(16) h2 s2w[100 * 52];   // rows padded to 52 pairs (zeros)
  __shared__ float s2b[100], s3w[100];
  __shared__ float s3b[1];
  const int tid = threadIdx.x;
  for (int i = tid; i < 100; i += 256) {
    s1w[i] = fc1w[i]; s1b[i] = fc1b[i]; s2b[i] = fc2b[i]; s3w[i] = fc3w[i];
  }
  for (int i = tid; i < 5200; i += 256) {
    int r = i / 52, c2 = i - 52 * r;
    s2w[i] = (c2 < 50) ? pkh2(fc2w[r * 100 + 2 * c2], fc2w[r * 100 + 2 * c2 + 1])
                       : pkh2(0.f, 0.f);
  }
  if (tid == 0) s3b[0] = fc3b[0];
  __syncthreads();

  const int sid = blockIdx.x * 256 + tid;
  if (sid >= B) return;
  const float y = out[sid];

  h2 a6[52];
  #pragma unroll
  for (int j2 = 0; j2 < 50; ++j2) {
    float t0 = tanhf_fast(y * s1w[2 * j2]     + s1b[2 * j2]);
    float t1 = tanhf_fast(y * s1w[2 * j2 + 1] + s1b[2 * j2 + 1]);
    a6[j2] = pkh2(t0, t1);
  }
  a6[50] = pkh2(0.f, 0.f);
  a6[51] = pkh2(0.f, 0.f);

  float logit = s3b[0];
  for (int i = 0; i < 100; ++i) {
    const f4a* row = (const f4a*)(s2w + i * 52);
    float acc0 = s2b[i], acc1 = 0.f;
    #pragma unroll
    for (int q = 0; q < 13; ++q) {
      float4 rv = row[q];
      acc0 = fdot2(f_h2(rv.x), a6[4*q+0], acc0);
      acc1 = fdot2(f_h2(rv.y), a6[4*q+1], acc1);
      acc0 = fdot2(f_h2(rv.z), a6[4*q+2], acc0);
      acc1 = fdot2(f_h2(rv.w), a6[4*q+3], acc1);
    }
    logit += tanhf_fast(acc0 + acc1) * s3w[i];
  }
  out[sid] = rcpf(1.f + __expf(-logit));
}

// ---------------------------------------------------------------------------
extern "C" void kernel_launch(void* const* d_in, const int* in_sizes, int n_in,
                              void* d_out, int out_size, void* d_ws, size_t ws_size,
                              hipStream_t stream) {
  (void)d_ws; (void)ws_size; (void)n_in; (void)out_size;
  const float* x     = (const float*)d_in[0];
  const float* kw    = (const float*)d_in[1];
  const float* kb    = (const float*)d_in[2];
  const float* qw    = (const float*)d_in[3];
  const float* qb    = (const float*)d_in[4];
  const float* vw    = (const float*)d_in[5];
  const float* vb    = (const float*)d_in[6];
  const float* kng   = (const float*)d_in[7];
  const float* knb   = (const float*)d_in[8];
  const float* qng   = (const float*)d_in[9];
  const float* qnb   = (const float*)d_in[10];
  const float* vng   = (const float*)d_in[11];
  const float* vnb   = (const float*)d_in[12];
  const float* klinw = (const float*)d_in[13];
  const float* klinb = (const float*)d_in[14];
  const float* qlinw = (const float*)d_in[15];
  const float* qlinb = (const float*)d_in[16];
  const float* alinw = (const float*)d_in[17];
  const float* alinb = (const float*)d_in[18];
  const float* l1w   = (const float*)d_in[19];
  const float* l1b   = (const float*)d_in[20];
  const float* l2w   = (const float*)d_in[21];
  const float* l2b   = (const float*)d_in[22];
  const float* fc1w  = (const float*)d_in[23];
  const float* fc1b  = (const float*)d_in[24];
  const float* fc2w  = (const float*)d_in[25];
  const float* fc2b  = (const float*)d_in[26];
  const float* fc3w  = (const float*)d_in[27];
  const float* fc3b  = (const float*)d_in[28];
  float* out = (float*)d_out;
  const int B = in_sizes[0] / 140;

  fused_main<<<512, 256, 0, stream>>>(x, kw, kb, qw, qb, vw, vb,
      kng, knb, qng, qnb, vng, vnb, klinw, klinb, qlinw, qlinb,
      alinw, alinb, l1w, l1b, l2w, l2b, out, B);
  mlp_head<<<(B + 255) / 256, 256, 0, stream>>>(out, fc1w, fc1b, fc2w, fc2b,
      fc3w, fc3b, B);
}

// Round 15
// 446.490 us; speedup vs baseline: 1.0744x; 1.0744x over previous
//
#include <hip/hip_runtime.h>

// ---------------------------------------------------------------------------
// Fused per-sample attention-critic network, MI355X (gfx950).
// r13 base (457us best: paired PV with per-head V register cache, lwr hoist)
// + r14's validated packed-f16 LN fast path ONLY (sequential PV reverted —
// it halved PV ILP and regressed; paired PV's 12MB spill costs less).
// ---------------------------------------------------------------------------

typedef __fp16 h2 __attribute__((ext_vector_type(2)));
typedef h2     h2a  __attribute__((may_alias));
typedef float4 f4a  __attribute__((may_alias));
typedef float2 f2a  __attribute__((may_alias));
typedef __fp16 f16a __attribute__((may_alias));

__device__ __forceinline__ h2 pkh2(float a, float b) {
#if __has_builtin(__builtin_amdgcn_cvt_pkrtz)
  return __builtin_amdgcn_cvt_pkrtz(a, b);
#else
  h2 r; r.x = (__fp16)a; r.y = (__fp16)b; return r;
#endif
}
__device__ __forceinline__ h2    f_h2(float f) { return __builtin_bit_cast(h2, f); }
__device__ __forceinline__ float h2_f(h2 v)    { return __builtin_bit_cast(float, v); }

__device__ __forceinline__ float fdot2(h2 a, h2 b, float c) {
#if __has_builtin(__builtin_amdgcn_fdot2)
  return __builtin_amdgcn_fdot2(a, b, c, false);
#else
  return c + (float)a.x * (float)b.x + (float)a.y * (float)b.y;
#endif
}
__device__ __forceinline__ float rcpf(float x) {
#if __has_builtin(__builtin_amdgcn_rcpf)
  return __builtin_amdgcn_rcpf(x);
#else
  return 1.f / x;
#endif
}
__device__ __forceinline__ float tanhf_fast(float x) {
  float e = __expf(2.f * x);                 // inf-safe
  return 1.f - 2.f * rcpf(e + 1.f);
}
__device__ __forceinline__ float eluf(float x) {
  return x > 0.f ? x : __expf(x) - 1.f;
}

#if __has_builtin(__builtin_amdgcn_update_dpp)
#define HAVE_DPP 1
#else
#define HAVE_DPP 0
#endif

// Full-wave (64-lane) f32 sum via DPP; result broadcast to all lanes.
__device__ __forceinline__ float wred_add(float x) {
#if HAVE_DPP
  float v = x;
  { int t = __builtin_amdgcn_update_dpp(0, __builtin_bit_cast(int, v), 0x111, 0xf, 0xf, true);
    v = v + __builtin_bit_cast(float, t); }   // row_shr:1
  { int t = __builtin_amdgcn_update_dpp(0, __builtin_bit_cast(int, v), 0x112, 0xf, 0xf, true);
    v = v + __builtin_bit_cast(float, t); }   // row_shr:2
  { int t = __builtin_amdgcn_update_dpp(0, __builtin_bit_cast(int, v), 0x114, 0xf, 0xf, true);
    v = v + __builtin_bit_cast(float, t); }   // row_shr:4
  { int t = __builtin_amdgcn_update_dpp(0, __builtin_bit_cast(int, v), 0x118, 0xf, 0xf, true);
    v = v + __builtin_bit_cast(float, t); }   // row_shr:8
  { int t = __builtin_amdgcn_update_dpp(0, __builtin_bit_cast(int, v), 0x142, 0xa, 0xf, true);
    v = v + __builtin_bit_cast(float, t); }   // row_bcast:15 -> rows 1,3
  { int t = __builtin_amdgcn_update_dpp(0, __builtin_bit_cast(int, v), 0x143, 0xc, 0xf, true);
    v = v + __builtin_bit_cast(float, t); }   // row_bcast:31 -> rows 2,3
  return __builtin_bit_cast(float, __builtin_amdgcn_readlane(__builtin_bit_cast(int, v), 63));
#else
  #pragma unroll
  for (int m2 = 1; m2 < 64; m2 <<= 1) x += __shfl_xor(x, m2, 64);
  return x;
#endif
}

// 16-lane (DPP-row) all-lane sum via rotate-accumulate.
__device__ __forceinline__ float dpp_add16(float x) {
#if HAVE_DPP
  float v = x;
  { int t = __builtin_amdgcn_update_dpp(0, __builtin_bit_cast(int, v), 0x121, 0xf, 0xf, true);
    v = v + __builtin_bit_cast(float, t); }   // row_ror:1
  { int t = __builtin_amdgcn_update_dpp(0, __builtin_bit_cast(int, v), 0x122, 0xf, 0xf, true);
    v = v + __builtin_bit_cast(float, t); }   // row_ror:2
  { int t = __builtin_amdgcn_update_dpp(0, __builtin_bit_cast(int, v), 0x124, 0xf, 0xf, true);
    v = v + __builtin_bit_cast(float, t); }   // row_ror:4
  { int t = __builtin_amdgcn_update_dpp(0, __builtin_bit_cast(int, v), 0x128, 0xf, 0xf, true);
    v = v + __builtin_bit_cast(float, t); }   // row_ror:8
  return v;
#else
  #pragma unroll
  for (int m2 = 1; m2 < 16; m2 <<= 1) x += __shfl_xor(x, m2, 64);
  return x;
#endif
}

// 16-lane (DPP-row) all-lane max via rotate-accumulate.
__device__ __forceinline__ float dpp_max16(float x) {
#if HAVE_DPP
  float v = x;
  { int t = __builtin_amdgcn_update_dpp(0, __builtin_bit_cast(int, v), 0x121, 0xf, 0xf, true);
    v = fmaxf(v, __builtin_bit_cast(float, t)); }
  { int t = __builtin_amdgcn_update_dpp(0, __builtin_bit_cast(int, v), 0x122, 0xf, 0xf, true);
    v = fmaxf(v, __builtin_bit_cast(float, t)); }
  { int t = __builtin_amdgcn_update_dpp(0, __builtin_bit_cast(int, v), 0x124, 0xf, 0xf, true);
    v = fmaxf(v, __builtin_bit_cast(float, t)); }
  { int t = __builtin_amdgcn_update_dpp(0, __builtin_bit_cast(int, v), 0x128, 0xf, 0xf, true);
    v = fmaxf(v, __builtin_bit_cast(float, t)); }
  return v;
#else
  #pragma unroll
  for (int m2 = 1; m2 < 16; m2 <<= 1) x = fmaxf(x, __shfl_xor(x, m2, 64));
  return x;
#endif
}

// ---------------------------------------------------------------------------
// s_mem (BYTES): staging [0,9728) dead after pre-loop reg loads (barrier),
// then 8 per-(wave,sample) arenas of 8352 B: wave wv owns
//   arenaA = s_mem + wv*16704, arenaB = arenaA + 8352.
// Arena: xs [0,288) 72 h2 | kqv [288,5664) 1344 h2 | Ab [5664,8352) 672 f32.
// (288+5376+2688 = 8352 exactly; identical to r8..r14 verified layout.)
// ---------------------------------------------------------------------------
__global__ __launch_bounds__(256, 2) void fused_main(
    const float* __restrict__ x,
    const float* __restrict__ kw,   const float* __restrict__ kb,
    const float* __restrict__ qw,   const float* __restrict__ qb,
    const float* __restrict__ vw,   const float* __restrict__ vb,
    const float* __restrict__ kng,  const float* __restrict__ knb,
    const float* __restrict__ qng,  const float* __restrict__ qnb,
    const float* __restrict__ vng,  const float* __restrict__ vnb,
    const float* __restrict__ klinw, const float* __restrict__ klinb,
    const float* __restrict__ qlinw, const float* __restrict__ qlinb,
    const float* __restrict__ alinw, const float* __restrict__ alinb,
    const float* __restrict__ l1w,  const float* __restrict__ l1b,
    const float* __restrict__ l2w,  const float* __restrict__ l2b,
    float* __restrict__ out, int B)
{
  __shared__ __align__(16) unsigned char s_mem[8 * 8352];  // 66816 B
  __shared__ __align__(16) h2 s_l1w[32 * 50];   // stride 100B, conflict-free
  __shared__ float s_l1b[32];
  __shared__ float s_l2w[32];
  __shared__ float s_l2b[1];
  __shared__ unsigned s_gflags;

  const int tid = threadIdx.x;

  // ---- staging views (valid only until the post-reg-load barrier) ----
  h2*    st_pw  = (h2*)(s_mem);
  float* st_pb  = (float*)(s_mem + 5760);
  h2*    st_qlw = (h2*)(s_mem + 6912);
  h2*    st_klw = (h2*)(s_mem + 7808);
  float* st_alw = (float*)(s_mem + 8704);
  float* st_bqk = (float*)(s_mem + 9600);
  float* st_ab  = (float*)(s_mem + 9664);

  for (int i = tid; i < 1440; i += 256) {
    int C = i / 5, f2 = i - 5 * C;
    int t = C / 96, c = C - 96 * t;
    const float* w = (t == 0) ? kw : (t == 1) ? qw : vw;
    st_pw[i] = pkh2(w[c * 10 + 2 * f2], w[c * 10 + 2 * f2 + 1]);
  }
  for (int i = tid; i < 288; i += 256) {
    int t = i / 96, c = i - 96 * t;
    st_pb[i] = ((t == 0) ? kb : (t == 1) ? qb : vb)[c];
  }
  for (int i = tid; i < 224; i += 256) {
    int n = i >> 4, d2 = i & 15;
    st_qlw[i] = pkh2(qlinw[n * 32 + 2 * d2], qlinw[n * 32 + 2 * d2 + 1]);
    st_klw[i] = pkh2(klinw[n * 32 + 2 * d2], klinw[n * 32 + 2 * d2 + 1]);
    st_alw[i] = (d2 < 14) ? alinw[n * 14 + d2] : 0.f;
  }
  if (tid < 14)             { st_bqk[tid] = qlinb[tid] + klinb[tid]; st_ab[tid] = alinb[tid]; }
  if (tid >= 14 && tid < 16){ st_bqk[tid] = 0.f; st_ab[tid] = 0.f; }
  for (int i = tid; i < 1600; i += 256) {
    int j = i / 50, c2 = i - 50 * j;
    s_l1w[i] = (c2 < 48) ? pkh2(l1w[j * 96 + 2 * c2], l1w[j * 96 + 2 * c2 + 1])
                         : pkh2(0.f, 0.f);
  }
  if (tid < 32) { s_l1b[tid] = l1b[tid]; s_l2w[tid] = l2w[tid]; }
  if (tid == 0) { s_l2b[0] = l2b[0]; s_gflags = 7u; }
  __syncthreads();
  for (int i = tid; i < 1344; i += 256) {
    if (kng[i] != 1.f || knb[i] != 0.f) atomicAnd(&s_gflags, ~1u);
    if (qng[i] != 1.f || qnb[i] != 0.f) atomicAnd(&s_gflags, ~2u);
    if (vng[i] != 1.f || vnb[i] != 0.f) atomicAnd(&s_gflags, ~4u);
  }
  __syncthreads();

  const int lane = tid & 63;
  const int wv   = tid >> 6;
  h2*    arenaA = (h2*)(s_mem + wv * 16704);
  h2*    arenaB = (h2*)(s_mem + wv * 16704 + 8352);
  h2     *xsA = arenaA, *xsB = arenaB;
  h2     *kqvA = arenaA + 72, *kqvB = arenaB + 72;        // h2 off 72 = byte 288
  f16a   *kqvhA = (f16a*)kqvA, *kqvhB = (f16a*)kqvB;
  float  *AbA = (float*)((unsigned char*)arenaA + 5664);
  float  *AbB = (float*)((unsigned char*)arenaB + 5664);
  const unsigned gf = s_gflags;

  // ---- persistent per-lane weight registers (from staging LDS, once) ----
  h2 pwA[3][5]; float pbA[3]; int cbA[3];
  #pragma unroll
  for (int k = 0; k < 3; ++k) {
    int C = lane + 64 * k;
    #pragma unroll
    for (int f2 = 0; f2 < 5; ++f2) pwA[k][f2] = st_pw[C * 5 + f2];
    pbA[k] = st_pb[C];
    int t = (C >= 96) ? 1 : 0, c = C - 96 * t;
    cbA[k] = t * 1344 + (c >> 5) * 448 + (c & 31);   // f16 idx (kqvh-relative)
  }
  h2 pwB[2][5]; float pbB[2]; int cbB[2]; bool actB[2];
  #pragma unroll
  for (int k = 0; k < 2; ++k) {
    int c = lane + 64 * k;
    actB[k] = (c < 96);
    int cc = actB[k] ? c : 0;
    #pragma unroll
    for (int f2 = 0; f2 < 5; ++f2) pwB[k][f2] = st_pw[(192 + cc) * 5 + f2];
    pbB[k] = st_pb[192 + cc];
    cbB[k] = (cc >> 5) * 448 + (cc & 31);
  }
  const int np  = lane & 15, grp = lane >> 4;
  const int npc = (np < 14) ? np : 0;
  h2 qwr[16], kwr[16];
  #pragma unroll
  for (int i = 0; i < 16; ++i) { qwr[i] = st_qlw[npc * 16 + i]; kwr[i] = st_klw[npc * 16 + i]; }
  const float bqkr = st_bqk[npc];
  float awr[14];
  #pragma unroll
  for (int i = 0; i < 14; ++i) awr[i] = st_alw[npc * 16 + i];
  const float abr  = st_ab[npc];
  const int j32 = lane & 31, g2 = lane >> 5;
  const float l1br = s_l1b[j32];
  const float l2r  = s_l2w[j32];
  const float l2bb = s_l2b[0];

  // staging is DEAD after this barrier; arenas become live
  __syncthreads();

  // l1 weights: loop-invariant -> hoist out of the pair loop
  h2 lwr[48];
  #pragma unroll
  for (int i = 0; i < 48; ++i) lwr[i] = s_l1w[j32 * 50 + i];

  h2 one2; one2.x = (__fp16)1.f; one2.y = (__fp16)1.f;
  const bool has3 = (lane < 40);               // 168 f4 chunks = 64+64+40

  // Paired LayerNorm over two 1344-f16 tensors (independent chains interleave)
  auto doLN2 = [&](h2* regA, h2* regB, const float* gp, const float* bp, bool triv) {
    const f4a* tA = (const f4a*)regA;
    const f4a* tB = (const f4a*)regB;
    float4 a0 = tA[lane],  a1 = tA[lane + 64], a2 = tA[has3 ? (lane + 128) : 0];
    float4 b0 = tB[lane],  b1 = tB[lane + 64], b2 = tB[has3 ? (lane + 128) : 0];
    if (!has3) { a2.x=a2.y=a2.z=a2.w=0.f; b2.x=b2.y=b2.z=b2.w=0.f; }
    float sA = 0.f, qA = 0.f, sB = 0.f, qB = 0.f;
    {
      float fa[12] = {a0.x,a0.y,a0.z,a0.w, a1.x,a1.y,a1.z,a1.w, a2.x,a2.y,a2.z,a2.w};
      float fb[12] = {b0.x,b0.y,b0.z,b0.w, b1.x,b1.y,b1.z,b1.w, b2.x,b2.y,b2.z,b2.w};
      #pragma unroll
      for (int i = 0; i < 12; ++i) {
        h2 ha = f_h2(fa[i]); sA = fdot2(ha, one2, sA); qA = fdot2(ha, ha, qA);
        h2 hb = f_h2(fb[i]); sB = fdot2(hb, one2, sB); qB = fdot2(hb, hb, qB);
      }
    }
    sA = wred_add(sA); qA = wred_add(qA);
    sB = wred_add(sB); qB = wred_add(qB);
    const float mA = sA * (1.f / 1344.f), mB = sB * (1.f / 1344.f);
    const float vA = qA * (1.f / 1344.f) - mA * mA;
    const float vB = qB * (1.f / 1344.f) - mB * mB;
    const float cA = rsqrtf(vA + 1e-5f),  cB = rsqrtf(vB + 1e-5f);
    const float dA = -mA * cA,            dB = -mB * cB;
    f4a* wA = (f4a*)regA;
    f4a* wB = (f4a*)regB;
    if (triv) {
      // packed f16 normalize: 1 v_pk_fma_f16 per h2 pair (validated in r14)
      h2 scA2 = pkh2(cA, cA), msA2 = pkh2(dA, dA);
      h2 scB2 = pkh2(cB, cB), msB2 = pkh2(dB, dB);
      auto nst = [&](float4 rv, int o, bool en, h2 s2, h2 m2, f4a* dst) {
        if (!en) return;
        float4 o4;
        o4.x = h2_f(f_h2(rv.x) * s2 + m2);
        o4.y = h2_f(f_h2(rv.y) * s2 + m2);
        o4.z = h2_f(f_h2(rv.z) * s2 + m2);
        o4.w = h2_f(f_h2(rv.w) * s2 + m2);
        dst[o] = o4;
      };
      nst(a0, lane,       true, scA2, msA2, wA); nst(b0, lane,       true, scB2, msB2, wB);
      nst(a1, lane + 64,  true, scA2, msA2, wA); nst(b1, lane + 64,  true, scB2, msB2, wB);
      nst(a2, lane + 128, has3, scA2, msA2, wA); nst(b2, lane + 128, has3, scB2, msB2, wB);
    } else {
      auto nstore = [&](float4 rv, int o, bool en, float sc, float msc, f4a* dst) {
        if (!en) return;
        h2 ha = f_h2(rv.x), hb = f_h2(rv.y), hc = f_h2(rv.z), hd = f_h2(rv.w);
        float f[8];
        f[0] = (float)ha.x * sc + msc; f[1] = (float)ha.y * sc + msc;
        f[2] = (float)hb.x * sc + msc; f[3] = (float)hb.y * sc + msc;
        f[4] = (float)hc.x * sc + msc; f[5] = (float)hc.y * sc + msc;
        f[6] = (float)hd.x * sc + msc; f[7] = (float)hd.y * sc + msc;
        #pragma unroll
        for (int i = 0; i < 8; ++i) { int e = 8 * o + i; f[i] = f[i] * gp[e] + bp[e]; }
        float4 o4;
        o4.x = h2_f(pkh2(f[0], f[1])); o4.y = h2_f(pkh2(f[2], f[3]));
        o4.z = h2_f(pkh2(f[4], f[5])); o4.w = h2_f(pkh2(f[6], f[7]));
        dst[o] = o4;
      };
      nstore(a0, lane,       true, cA, dA, wA); nstore(b0, lane,       true, cB, dB, wB);
      nstore(a1, lane + 64,  true, cA, dA, wA); nstore(b1, lane + 64,  true, cB, dB, wB);
      nstore(a2, lane + 128, has3, cA, dA, wA); nstore(b2, lane + 128, has3, cB, dB, wB);
    }
  };

  const int pid = blockIdx.x * 4 + wv;      // pair index
  const int pstr = gridDim.x * 4;

  for (int s0 = pid * 2; s0 < B; s0 += pstr * 2) {
    const int s1 = s0 + 1;
    const bool has1 = (s1 < B);
    const int s1c = has1 ? s1 : s0;

    // ---------------- stage x (2 samples) ----------------
    const f2a* xpA = (const f2a*)(x + (size_t)s0  * 140);
    const f2a* xpB = (const f2a*)(x + (size_t)s1c * 140);
    { f2a vA = xpA[lane], vB = xpB[lane];
      xsA[lane] = pkh2(vA.x, vA.y); xsB[lane] = pkh2(vB.x, vB.y); }
    if (lane < 6) {
      f2a vA = xpA[64 + lane], vB = xpB[64 + lane];
      xsA[64 + lane] = pkh2(vA.x, vA.y); xsB[64 + lane] = pkh2(vB.x, vB.y);
    }

    // ============ PHASE A: K,Q projections (paired) ============
    for (int n = 0; n < 14; ++n) {
      h2 a0=xsA[n*5+0],a1=xsA[n*5+1],a2=xsA[n*5+2],a3=xsA[n*5+3],a4=xsA[n*5+4];
      h2 c0=xsB[n*5+0],c1=xsB[n*5+1],c2=xsB[n*5+2],c3=xsB[n*5+3],c4=xsB[n*5+4];
      #pragma unroll
      for (int k = 0; k < 3; ++k) {
        float uA = pbA[k], uB = pbA[k];
        uA = fdot2(a0, pwA[k][0], uA); uB = fdot2(c0, pwA[k][0], uB);
        uA = fdot2(a1, pwA[k][1], uA); uB = fdot2(c1, pwA[k][1], uB);
        uA = fdot2(a2, pwA[k][2], uA); uB = fdot2(c2, pwA[k][2], uB);
        uA = fdot2(a3, pwA[k][3], uA); uB = fdot2(c3, pwA[k][3], uB);
        uA = fdot2(a4, pwA[k][4], uA); uB = fdot2(c4, pwA[k][4], uB);
        kqvhA[cbA[k] + n * 32] = (__fp16)uA;
        kqvhB[cbA[k] + n * 32] = (__fp16)uB;
      }
    }
    doLN2(kqvA,       kqvB,       kng, knb, (gf >> 0) & 1u);   // K pair
    doLN2(kqvA + 672, kqvB + 672, qng, qnb, (gf >> 1) & 1u);   // Q pair

    // ------- scores (paired): elu(Q·qlw + K·klw + b) -------
    for (int k = 0; k <= 10; ++k) {
      int r = grp + 4 * k;
      bool act = (np < 14) && (r < 42);
      int rr = (r < 42) ? r : 0;
      const f4a* KrA = (const f4a*)(kqvA + rr * 16);
      const f4a* QrA = (const f4a*)(kqvA + 672 + rr * 16);
      const f4a* KrB = (const f4a*)(kqvB + rr * 16);
      const f4a* QrB = (const f4a*)(kqvB + 672 + rr * 16);
      float aqA = bqkr, akA = 0.f, aqB = bqkr, akB = 0.f;
      #pragma unroll
      for (int q = 0; q < 4; ++q) {
        float4 qvA = QrA[q], kvA = KrA[q], qvB = QrB[q], kvB = KrB[q];
        aqA = fdot2(f_h2(qvA.x), qwr[4*q+0], aqA); aqB = fdot2(f_h2(qvB.x), qwr[4*q+0], aqB);
        aqA = fdot2(f_h2(qvA.y), qwr[4*q+1], aqA); aqB = fdot2(f_h2(qvB.y), qwr[4*q+1], aqB);
        aqA = fdot2(f_h2(qvA.z), qwr[4*q+2], aqA); aqB = fdot2(f_h2(qvB.z), qwr[4*q+2], aqB);
        aqA = fdot2(f_h2(qvA.w), qwr[4*q+3], aqA); aqB = fdot2(f_h2(qvB.w), qwr[4*q+3], aqB);
        akA = fdot2(f_h2(kvA.x), kwr[4*q+0], akA); akB = fdot2(f_h2(kvB.x), kwr[4*q+0], akB);
        akA = fdot2(f_h2(kvA.y), kwr[4*q+1], akA); akB = fdot2(f_h2(kvB.y), kwr[4*q+1], akB);
        akA = fdot2(f_h2(kvA.z), kwr[4*q+2], akA); akB = fdot2(f_h2(kvB.z), kwr[4*q+2], akB);
        akA = fdot2(f_h2(kvA.w), kwr[4*q+3], akA); akB = fdot2(f_h2(kvB.w), kwr[4*q+3], akB);
      }
      float aA = eluf(aqA + akA), aB = eluf(aqB + akB);
      if (act) { AbA[rr * 16 + np] = aA; AbB[rr * 16 + np] = aB; }
    }

    // ------- alin + softmax (paired; DPP row reductions) -------
    for (int k = 0; k <= 10; ++k) {
      int r = grp + 4 * k;
      bool act = (np < 14) && (r < 42);
      int rr = (r < 42) ? r : 0;
      const f4a* SA = (const f4a*)(AbA + rr * 16);
      const f4a* SB = (const f4a*)(AbB + rr * 16);
      float4 A0 = SA[0], A1 = SA[1], A2 = SA[2], A3 = SA[3];
      float4 B0 = SB[0], B1 = SB[1], B2 = SB[2], B3 = SB[3];
      float prA[14] = {A0.x,A0.y,A0.z,A0.w, A1.x,A1.y,A1.z,A1.w,
                       A2.x,A2.y,A2.z,A2.w, A3.x,A3.y};
      float prB[14] = {B0.x,B0.y,B0.z,B0.w, B1.x,B1.y,B1.z,B1.w,
                       B2.x,B2.y,B2.z,B2.w, B3.x,B3.y};
      float acA = abr, acB = abr;
      #pragma unroll
      for (int i = 0; i < 14; ++i) { acA += prA[i] * awr[i]; acB += prB[i] * awr[i]; }
      float vA = act ? acA : -__builtin_inff();
      float vB = act ? acB : -__builtin_inff();
      float mA = dpp_max16(vA);
      float mB = dpp_max16(vB);
      float eA = __expf(vA - mA), eB = __expf(vB - mB);   // inactive lanes -> 0
      float sA = dpp_add16(eA);
      float sB = dpp_add16(eB);
      float pA = eA * rcpf(sA), pB = eB * rcpf(sB);
      if (act) { AbA[rr * 16 + np] = pA; AbB[rr * 16 + np] = pB; }
    }

    // ============ PHASE B: V projection (paired, overlays K) ============
    for (int n = 0; n < 14; ++n) {
      h2 a0=xsA[n*5+0],a1=xsA[n*5+1],a2=xsA[n*5+2],a3=xsA[n*5+3],a4=xsA[n*5+4];
      h2 c0=xsB[n*5+0],c1=xsB[n*5+1],c2=xsB[n*5+2],c3=xsB[n*5+3],c4=xsB[n*5+4];
      #pragma unroll
      for (int k = 0; k < 2; ++k) {
        float uA = pbB[k], uB = pbB[k];
        uA = fdot2(a0, pwB[k][0], uA); uB = fdot2(c0, pwB[k][0], uB);
        uA = fdot2(a1, pwB[k][1], uA); uB = fdot2(c1, pwB[k][1], uB);
        uA = fdot2(a2, pwB[k][2], uA); uB = fdot2(c2, pwB[k][2], uB);
        uA = fdot2(a3, pwB[k][3], uA); uB = fdot2(c3, pwB[k][3], uB);
        uA = fdot2(a4, pwB[k][4], uA); uB = fdot2(c4, pwB[k][4], uB);
        if (actB[k]) {
          kqvhA[cbB[k] + n * 32] = (__fp16)uA;
          kqvhB[cbB[k] + n * 32] = (__fp16)uB;
        }
      }
    }
    doLN2(kqvA, kqvB, vng, vnb, (gf >> 2) & 1u);   // V pair (overlaid K region)

    // ------- E = A@V (paired; V register-cached per head, r13 form) -------
    #pragma unroll
    for (int h = 0; h < 3; ++h) {
      h2 vregA[14], vregB[14];
      {
        const h2a* VA = (const h2a*)(kqvA + h * 224 + np);
        const h2a* VB = (const h2a*)(kqvB + h * 224 + np);
        #pragma unroll
        for (int m = 0; m < 14; ++m) { vregA[m] = VA[m * 16]; vregB[m] = VB[m * 16]; }
      }
      const int base = h * 14 + ((grp + 2 * (h & 1)) & 3);
      #pragma unroll
      for (int i = 0; i < 4; ++i) {
        int rr = base + 4 * i;
        bool act = (rr < h * 14 + 14);
        int rrc = act ? rr : h * 14;
        int n = rrc - 14 * h;
        const f4a* PA = (const f4a*)(AbA + rrc * 16);
        const f4a* PB = (const f4a*)(AbB + rrc * 16);
        float4 A0 = PA[0], A1 = PA[1], A2 = PA[2], A3 = PA[3];
        float4 B0 = PB[0], B1 = PB[1], B2 = PB[2], B3 = PB[3];
        float prA[14] = {A0.x,A0.y,A0.z,A0.w, A1.x,A1.y,A1.z,A1.w,
                         A2.x,A2.y,A2.z,A2.w, A3.x,A3.y};
        float prB[14] = {B0.x,B0.y,B0.z,B0.w, B1.x,B1.y,B1.z,B1.w,
                         B2.x,B2.y,B2.z,B2.w, B3.x,B3.y};
        float axA = 0.f, ayA = 0.f, axB = 0.f, ayB = 0.f;
        #pragma unroll
        for (int m = 0; m < 14; ++m) {
          axA += prA[m] * (float)vregA[m].x; ayA += prA[m] * (float)vregA[m].y;
          axB += prB[m] * (float)vregB[m].x; ayB += prB[m] * (float)vregB[m].y;
        }
        if (act) {
          kqvA[672 + n * 48 + h * 16 + np] = pkh2(axA, ayA);
          kqvB[672 + n * 48 + h * 16 + np] = pkh2(axB, ayB);
        }
      }
    }

    // ------- l1 (paired, hoisted lwr): E2 = relu(E·l1w + b) -------
    for (int k = 0; k < 7; ++k) {
      int n = g2 + 2 * k;
      const f4a* EA = (const f4a*)(kqvA + 672 + n * 48);
      const f4a* EB = (const f4a*)(kqvB + 672 + n * 48);
      float u0A = l1br, u1A = 0.f, u0B = l1br, u1B = 0.f;
      #pragma unroll
      for (int q = 0; q < 12; ++q) {
        float4 eA = EA[q], eB = EB[q];
        u0A = fdot2(f_h2(eA.x), lwr[4*q+0], u0A); u0B = fdot2(f_h2(eB.x), lwr[4*q+0], u0B);
        u1A = fdot2(f_h2(eA.y), lwr[4*q+1], u1A); u1B = fdot2(f_h2(eB.y), lwr[4*q+1], u1B);
        u0A = fdot2(f_h2(eA.z), lwr[4*q+2], u0A); u0B = fdot2(f_h2(eB.z), lwr[4*q+2], u0B);
        u1A = fdot2(f_h2(eA.w), lwr[4*q+3], u1A); u1B = fdot2(f_h2(eB.w), lwr[4*q+3], u1B);
      }
      AbA[n * 32 + j32] = fmaxf(u0A + u1A, 0.f);
      AbB[n * 32 + j32] = fmaxf(u0B + u1B, 0.f);
    }

    // ------- LN2 (paired, DPP) + max_n + l2 -> y -------
    {
      float vlA[7], vlB[7];
      #pragma unroll
      for (int m = 0; m < 7; ++m) { vlA[m] = AbA[lane + 64 * m]; vlB[m] = AbB[lane + 64 * m]; }
      float sA = 0.f, qA = 0.f, sB = 0.f, qB = 0.f;
      #pragma unroll
      for (int m = 0; m < 7; ++m) {
        sA += vlA[m]; qA += vlA[m] * vlA[m];
        sB += vlB[m]; qB += vlB[m] * vlB[m];
      }
      sA = wred_add(sA); qA = wred_add(qA);
      sB = wred_add(sB); qB = wred_add(qB);
      float mnA = sA * (1.f / 448.f), mnB = sB * (1.f / 448.f);
      float vrA = qA * (1.f / 448.f) - mnA * mnA;
      float vrB = qB * (1.f / 448.f) - mnB * mnB;
      float scA = rsqrtf(vrA + 1e-5f), scB = rsqrtf(vrB + 1e-5f);
      float mxA = -__builtin_inff(), mxB = -__builtin_inff();
      #pragma unroll
      for (int k = 0; k < 7; ++k) {
        mxA = fmaxf(mxA, AbA[(g2 + 2 * k) * 32 + j32]);
        mxB = fmaxf(mxB, AbB[(g2 + 2 * k) * 32 + j32]);
      }
      mxA = fmaxf(mxA, __shfl_xor(mxA, 32, 64));
      mxB = fmaxf(mxB, __shfl_xor(mxB, 32, 64));
      float MdA = (mxA - mnA) * scA;            // scale>0: max commutes with LN
      float MdB = (mxB - mnB) * scB;
      float vdA = wred_add((lane < 32) ? MdA * l2r : 0.f);
      float vdB = wred_add((lane < 32) ? MdB * l2r : 0.f);
      float yA = eluf(vdA + l2bb), yB = eluf(vdB + l2bb);
      if (lane == 0) { out[s0] = yA; if (has1) out[s1] = yB; }
    }
  }
}

// ---------------------------------------------------------------------------
// Kernel 2: out[s] = sigmoid(fc3 · tanh(fc2 · tanh(fc1*y + b1) + b2) + b3)
// Applied in place on d_out (kernel 1 left y there).
// ---------------------------------------------------------------------------
__global__ __launch_bounds__(256) void mlp_head(
    float* __restrict__ out,
    const float* __restrict__ fc1w, const float* __restrict__ fc1b,
    const float* __restrict__ fc2w, const float* __restrict__ fc2b,
    const float* __restrict__ fc3w, const float* __restrict__ fc3b, int B)
{
  __shared__ float s1w[100], s1b[100];
  __shared__ __align__(16) h2 s2w[100 * 52];   // rows padded to 52 pairs (zeros)
  __shared__ float s2b[100], s3w[100];
  __shared__ float s3b[1];
  const int tid = threadIdx.x;
  for (int i = tid; i < 100; i += 256) {
    s1w[i] = fc1w[i]; s1b[i] = fc1b[i]; s2b[i] = fc2b[i]; s3w[i] = fc3w[i];
  }
  for (int i = tid; i < 5200; i += 256) {
    int r = i / 52, c2 = i - 52 * r;
    s2w[i] = (c2 < 50) ? pkh2(fc2w[r * 100 + 2 * c2], fc2w[r * 100 + 2 * c2 + 1])
                       : pkh2(0.f, 0.f);
  }
  if (tid == 0) s3b[0] = fc3b[0];
  __syncthreads();

  const int sid = blockIdx.x * 256 + tid;
  if (sid >= B) return;
  const float y = out[sid];

  h2 a6[52];
  #pragma unroll
  for (int j2 = 0; j2 < 50; ++j2) {
    float t0 = tanhf_fast(y * s1w[2 * j2]     + s1b[2 * j2]);
    float t1 = tanhf_fast(y * s1w[2 * j2 + 1] + s1b[2 * j2 + 1]);
    a6[j2] = pkh2(t0, t1);
  }
  a6[50] = pkh2(0.f, 0.f);
  a6[51] = pkh2(0.f, 0.f);

  float logit = s3b[0];
  for (int i = 0; i < 100; ++i) {
    const f4a* row = (const f4a*)(s2w + i * 52);
    float acc0 = s2b[i], acc1 = 0.f;
    #pragma unroll
    for (int q = 0; q < 13; ++q) {
      float4 rv = row[q];
      acc0 = fdot2(f_h2(rv.x), a6[4*q+0], acc0);
      acc1 = fdot2(f_h2(rv.y), a6[4*q+1], acc1);
      acc0 = fdot2(f_h2(rv.z), a6[4*q+2], acc0);
      acc1 = fdot2(f_h2(rv.w), a6[4*q+3], acc1);
    }
    logit += tanhf_fast(acc0 + acc1) * s3w[i];
  }
  out[sid] = rcpf(1.f + __expf(-logit));
}

// ---------------------------------------------------------------------------
extern "C" void kernel_launch(void* const* d_in, const int* in_sizes, int n_in,
                              void* d_out, int out_size, void* d_ws, size_t ws_size,
                              hipStream_t stream) {
  (void)d_ws; (void)ws_size; (void)n_in; (void)out_size;
  const float* x     = (const float*)d_in[0];
  const float* kw    = (const float*)d_in[1];
  const float* kb    = (const float*)d_in[2];
  const float* qw    = (const float*)d_in[3];
  const float* qb    = (const float*)d_in[4];
  const float* vw    = (const float*)d_in[5];
  const float* vb    = (const float*)d_in[6];
  const float* kng   = (const float*)d_in[7];
  const float* knb   = (const float*)d_in[8];
  const float* qng   = (const float*)d_in[9];
  const float* qnb   = (const float*)d_in[10];
  const float* vng   = (const float*)d_in[11];
  const float* vnb   = (const float*)d_in[12];
  const float* klinw = (const float*)d_in[13];
  const float* klinb = (const float*)d_in[14];
  const float* qlinw = (const float*)d_in[15];
  const float* qlinb = (const float*)d_in[16];
  const float* alinw = (const float*)d_in[17];
  const float* alinb = (const float*)d_in[18];
  const float* l1w   = (const float*)d_in[19];
  const float* l1b   = (const float*)d_in[20];
  const float* l2w   = (const float*)d_in[21];
  const float* l2b   = (const float*)d_in[22];
  const float* fc1w  = (const float*)d_in[23];
  const float* fc1b  = (const float*)d_in[24];
  const float* fc2w  = (const float*)d_in[25];
  const float* fc2b  = (const float*)d_in[26];
  const float* fc3w  = (const float*)d_in[27];
  const float* fc3b  = (const float*)d_in[28];
  float* out = (float*)d_out;
  const int B = in_sizes[0] / 140;

  fused_main<<<512, 256, 0, stream>>>(x, kw, kb, qw, qb, vw, vb,
      kng, knb, qng, qnb, vng, vnb, klinw, klinb, qlinw, qlinb,
      alinw, alinb, l1w, l1b, l2w, l2b, out, B);
  mlp_head<<<(B + 255) / 256, 256, 0, stream>>>(out, fc1w, fc1b, fc2w, fc2b,
      fc3w, fc3b, B);
}